// Round 14
// baseline (114.339 us; speedup 1.0000x reference)
//
#include <hip/hip_runtime.h>

#define B_ 4
#define N_ 2048
#define C_ 512
#define H_ 8
#define HD_ 64
#define SCALE_ 0.125f
// SCALE * log2(e): Q is pre-scaled by this so P = exp2(q.k) directly (v_exp_f32)
#define QSCALE_ 0.18033688011112042f

typedef __attribute__((ext_vector_type(8))) __bf16 bf16x8;
typedef __attribute__((ext_vector_type(4))) float f32x4;
typedef __attribute__((ext_vector_type(4))) unsigned int u32x4;
typedef __attribute__((ext_vector_type(2))) unsigned int u32x2;
typedef __attribute__((ext_vector_type(4))) short s16x4;

#if __has_builtin(__builtin_amdgcn_mfma_f32_16x16x16bf16_1k)
#define MFMA16(acc, a, b) acc = __builtin_amdgcn_mfma_f32_16x16x16bf16_1k(a, b, acc, 0, 0, 0)
#else
#define MFMA16(acc, a, b) \
    asm("v_mfma_f32_16x16x16_bf16 %0, %1, %2, %0" : "+v"(acc) : "v"(a), "v"(b))
#endif

__device__ __forceinline__ unsigned short f2bf(float f) {
    unsigned int u = __builtin_bit_cast(unsigned int, f);
    u += 0x7fffu + ((u >> 16) & 1u);
    return (unsigned short)(u >> 16);
}

__device__ __forceinline__ void llds16(const void* g, void* l) {
    __builtin_amdgcn_global_load_lds(
        (const __attribute__((address_space(1))) unsigned int*)g,
        (__attribute__((address_space(3))) unsigned int*)l, 16, 0, 0);
}

// ---------------------------------------------------------------- convert (x, w_qkv, w_proj fused)
__global__ __launch_bounds__(256) void cvt_all(const float* __restrict__ x,
                                               const float* __restrict__ wq,
                                               const float* __restrict__ wp,
                                               unsigned short* __restrict__ xb,
                                               unsigned short* __restrict__ wqb,
                                               unsigned short* __restrict__ wpb) {
    const int NX = B_ * N_ * C_ / 4, NQ = 3 * C_ * C_ / 4, NP = C_ * C_ / 4;
    int i = blockIdx.x * 256 + threadIdx.x;
    const float4* src;
    ushort4* dst;
    int idx;
    if (i < NX) { src = (const float4*)x; dst = (ushort4*)xb; idx = i; }
    else if (i < NX + NQ) { src = (const float4*)wq; dst = (ushort4*)wqb; idx = i - NX; }
    else if (i < NX + NQ + NP) { src = (const float4*)wp; dst = (ushort4*)wpb; idx = i - NX - NQ; }
    else return;
    float4 v = src[idx];
    ushort4 o;
    o.x = f2bf(v.x); o.y = f2bf(v.y); o.z = f2bf(v.z); o.w = f2bf(v.w);
    dst[idx] = o;
}

// ---------------------------------------------------------------- GEMM (B^T input layout)
// C[m][c] = sum_k A[m][k] * Bw[c][k] + bias[c]
// MODE 0: A = xb (8192x512), Bw = w_qkv bf16 (1536x512).
//   n0 < 1024  (Q/K blocks): direct coalesced (B,H,N,64) writes; Q pre-scaled QSCALE_.
//   n0 >= 1024 (V blocks): 128x128 tile transposed via LDS (XOR-swizzled), then
//   COALESCED d-major write to Vt (B,H,64,N).
// MODE 1: A = AO (8192x512), Bw = w_proj bf16 (512x512); f32 epilogue -> Out
template <int MODE>
__global__ __launch_bounds__(256) void gemm_bt(const unsigned short* __restrict__ A,
                                               const unsigned short* __restrict__ Bw,
                                               const float* __restrict__ bias,
                                               float* __restrict__ Out,
                                               unsigned short* __restrict__ Qb,
                                               unsigned short* __restrict__ Kb,
                                               unsigned short* __restrict__ Vt) {
    constexpr int K = 512;
    __shared__ __align__(16) unsigned char smem[32768];
    unsigned char* sA = smem;
    unsigned char* sB = smem + 16384;

    const int tid = threadIdx.x;
    const int lane = tid & 63;
    const int wave = tid >> 6;
    const int wm = wave >> 1, wn = wave & 1;
    const int m0 = blockIdx.y * 128;
    const int n0 = blockIdx.x * 128;

    f32x4 acc[4][4] = {};

    for (int k0 = 0; k0 < K; k0 += 64) {
#pragma unroll
        for (int i = 0; i < 4; i++) {
            int ci = wave * 4 + i;
            int row = ci * 8 + (lane >> 3);
            int cb = (lane & 7) * 16;
            const unsigned char* ga =
                (const unsigned char*)A + ((size_t)(m0 + row) * K + k0) * 2 + cb;
            const unsigned char* gb =
                (const unsigned char*)Bw + ((size_t)(n0 + row) * K + k0) * 2 + cb;
            llds16(ga, sA + ci * 1024);
            llds16(gb, sB + ci * 1024);
        }
        __syncthreads();
#pragma unroll
        for (int kk = 0; kk < 2; kk++) {
            bf16x8 af[4], bfr[4];
#pragma unroll
            for (int mi = 0; mi < 4; mi++)
                af[mi] = *(const bf16x8*)(sA + (wm * 64 + mi * 16 + (lane & 15)) * 128 +
                                          kk * 64 + (lane >> 4) * 16);
#pragma unroll
            for (int ni = 0; ni < 4; ni++)
                bfr[ni] = *(const bf16x8*)(sB + (wn * 64 + ni * 16 + (lane & 15)) * 128 +
                                           kk * 64 + (lane >> 4) * 16);
#pragma unroll
            for (int mi = 0; mi < 4; mi++)
#pragma unroll
                for (int ni = 0; ni < 4; ni++)
                    acc[mi][ni] = __builtin_amdgcn_mfma_f32_16x16x32_bf16(
                        af[mi], bfr[ni], acc[mi][ni], 0, 0, 0);
        }
        __syncthreads();
    }

    if constexpr (MODE == 0) {
        if (n0 >= 1024) {
            // ---- V blocks: LDS transpose then coalesced d-major write
            unsigned char* T = smem;  // [128 c][128 m] bf16, byte = cl*256 + (ml*2 ^ ((cl&7)<<4))
#pragma unroll
            for (int ni = 0; ni < 4; ni++) {
                int cl = wn * 64 + ni * 16 + (lane & 15);
                float bv = bias[n0 + cl];
#pragma unroll
                for (int mi = 0; mi < 4; mi++) {
#pragma unroll
                    for (int r = 0; r < 4; r++) {
                        int ml = wm * 64 + mi * 16 + ((lane >> 4) << 2) + r;
                        *(unsigned short*)(T + cl * 256 + ((ml * 2) ^ ((cl & 7) << 4))) =
                            f2bf(acc[mi][ni][r] + bv);
                    }
                }
            }
            __syncthreads();
            const int b = m0 >> 11;
#pragma unroll
            for (int it = 0; it < 8; it++) {
                int li = it * 256 + tid;
                int cl2 = li >> 4, mc = li & 15;
                int cg = n0 + cl2;
                int h = (cg >> 6) & 7, d = cg & 63;
                u32x4 vv = *(const u32x4*)(T + cl2 * 256 + ((mc * 16) ^ ((cl2 & 7) << 4)));
                int n = (m0 & (N_ - 1)) + mc * 8;
                *(u32x4*)((unsigned char*)Vt +
                          (((size_t)(b * H_ + h) * HD_ + d) * N_ + n) * 2) = vv;
            }
        } else {
            // ---- Q/K blocks: direct coalesced (B,H,N,64) writes
            const bool selq = (n0 < 512);
#pragma unroll
            for (int ni = 0; ni < 4; ni++) {
                int cg = n0 + wn * 64 + ni * 16 + (lane & 15);
                int h = (cg >> 6) & 7, d = cg & 63;
                float bv = bias[cg];
#pragma unroll
                for (int mi = 0; mi < 4; mi++) {
#pragma unroll
                    for (int r = 0; r < 4; r++) {
                        int m = m0 + wm * 64 + mi * 16 + ((lane >> 4) << 2) + r;
                        int b = m >> 11, n = m & (N_ - 1);
                        float fv = acc[mi][ni][r] + bv;
                        size_t idx = ((size_t)(b * H_ + h) * N_ + n) * HD_ + d;
                        if (selq) Qb[idx] = f2bf(fv * QSCALE_);
                        else Kb[idx] = f2bf(fv);
                    }
                }
            }
        }
    } else {
#pragma unroll
        for (int ni = 0; ni < 4; ni++) {
            int c = n0 + wn * 64 + ni * 16 + (lane & 15);
            float bv = bias[c];
#pragma unroll
            for (int mi = 0; mi < 4; mi++) {
#pragma unroll
                for (int r = 0; r < 4; r++) {
                    int m = m0 + wm * 64 + mi * 16 + ((lane >> 4) << 2) + r;
                    Out[(size_t)m * C_ + c] = acc[mi][ni][r] + bv;
                }
            }
        }
    }
}

// ---------------------------------------------------------------- flash attention
// grid: 512 XCD-swizzled blocks; 8 waves = 4 q-groups x 2 kv-halves. Each wave:
// 32 q-rows (2 subtiles u) x 32 kv — same cells/wave as R13 but HALF the LDS
// K/V fragment reads (the R13 LDS-pipe bottleneck, ~68% busy). Post-loop the
// kv-halves combine via one LDS exchange. Swapped QK^T -> in-register P (K=16
// PV MFMAs); no-max exp2 softmax; ones-MFMA row sums.
__global__ __launch_bounds__(512, 4) void attn_fwd(const unsigned short* __restrict__ Qb,
                                                   const unsigned short* __restrict__ Kb,
                                                   const unsigned short* __restrict__ Vt,
                                                   unsigned short* __restrict__ AO) {
    __shared__ __align__(16) unsigned char smem[40960];
    // staging: sK buf0/1 at 0,8192 | sV buf0/1 at 16384,24576 (32KB)
    // post-loop combine reuses [0, 40960): 4 regions x 64 lanes x 160B

    const int tid = threadIdx.x, lane = tid & 63, wave = tid >> 6;
    const int g = lane >> 4, c = lane & 15;
    const int wq = wave >> 1, wk = wave & 1;
    // XCD-aware bijective swizzle: each XCD (L%8) owns 4 complete bh's.
    const int L = blockIdx.y * 16 + blockIdx.x;
    const int bh = (L & 7) * 4 + ((L >> 3) & 3);
    const int qx = L >> 5;
    const int q0 = qx * 128 + wq * 32;
    const unsigned short* Qh = Qb + (size_t)bh * N_ * HD_;
    const unsigned short* Kh = Kb + (size_t)bh * N_ * HD_;
    const unsigned short* Vh = Vt + (size_t)bh * HD_ * N_;

    // Q fragments for both 16-row subtiles (B-operand of swapped QK)
    bf16x8 qf[2][2];
#pragma unroll
    for (int u = 0; u < 2; u++)
#pragma unroll
        for (int kk = 0; kk < 2; kk++)
            qf[u][kk] = *(const bf16x8*)(Qh + (size_t)(q0 + u * 16 + c) * HD_ +
                                         kk * 32 + g * 8);

    s16x4 ones16;
#pragma unroll
    for (int i = 0; i < 4; i++) ones16[i] = (short)0x3F80;  // bf16 1.0

    f32x4 o[2][4] = {};
    f32x4 osum[2] = {};

    // staging geometry (all 512 threads stage the full 64-kv tile)
    const int srow = tid >> 3;
    const int sslot = (tid & 7) * 16;
    const int ssw = (sslot ^ ((srow & 7) << 4));

    // prologue: stage tile 0 into buf 0
    {
        u32x4 kreg = *(const u32x4*)((const unsigned char*)Kh + (size_t)srow * 128 + sslot);
        u32x4 vreg = *(const u32x4*)((const unsigned char*)Vh + (size_t)srow * (N_ * 2) + sslot);
        *(u32x4*)(smem + srow * 128 + ssw) = kreg;
        *(u32x4*)(smem + 16384 + srow * 128 + ssw) = vreg;
    }
    __syncthreads();

#pragma unroll 1
    for (int t = 0; t < N_ / 64; t++) {
        unsigned char* bK = smem + (t & 1) * 8192;
        unsigned char* bV = smem + 16384 + (t & 1) * 8192;

        // ---- issue next tile's global loads (latency hides under compute)
        u32x4 kreg, vreg;
        if (t < N_ / 64 - 1) {
            int kv0 = (t + 1) * 64;
            kreg = *(const u32x4*)((const unsigned char*)Kh + (size_t)(kv0 + srow) * 128 + sslot);
            vreg = *(const u32x4*)((const unsigned char*)Vh + (size_t)srow * (N_ * 2) +
                                   kv0 * 2 + sslot);
        }

        // ---- S^T = K Q^T over this wave's kv-half: lane holds
        //      S[q = q0+u*16+c][kv = wk*32 + j*16 + 4g + r]
        f32x4 s[2][2] = {};
#pragma unroll
        for (int j = 0; j < 2; j++) {
#pragma unroll
            for (int kk = 0; kk < 2; kk++) {
                int krow = wk * 32 + j * 16 + c;
                bf16x8 kf = *(const bf16x8*)(bK + krow * 128 +
                                             ((kk * 64 + g * 16) ^ ((krow & 7) << 4)));
                s[0][j] = __builtin_amdgcn_mfma_f32_16x16x32_bf16(kf, qf[0][kk], s[0][j], 0, 0, 0);
                s[1][j] = __builtin_amdgcn_mfma_f32_16x16x32_bf16(kf, qf[1][kk], s[1][j], 0, 0, 0);
            }
        }

        // ---- P = exp2(S^T); pack in-register into K=16 A-fragments
        s16x4 pa[2][2];
#pragma unroll
        for (int u = 0; u < 2; u++)
#pragma unroll
            for (int j = 0; j < 2; j++) {
                float p0 = __builtin_exp2f(s[u][j][0]);
                float p1 = __builtin_exp2f(s[u][j][1]);
                float p2 = __builtin_exp2f(s[u][j][2]);
                float p3 = __builtin_exp2f(s[u][j][3]);
                unsigned int lo, hi;
                asm("v_cvt_pk_bf16_f32 %0, %1, %2" : "=v"(lo) : "v"(p0), "v"(p1));
                asm("v_cvt_pk_bf16_f32 %0, %1, %2" : "=v"(hi) : "v"(p2), "v"(p3));
                u32x2 w;
                w[0] = lo;
                w[1] = hi;
                pa[u][j] = __builtin_bit_cast(s16x4, w);
            }

        // ---- O += P V and rowsum += P*ones over the kv-half (V fragment shared by u)
#pragma unroll
        for (int j = 0; j < 2; j++) {
            MFMA16(osum[0], pa[0][j], ones16);
            MFMA16(osum[1], pa[1][j], ones16);
#pragma unroll
            for (int dj = 0; dj < 4; dj++) {
                int vrow = dj * 16 + c;
                u32x2 vv = *(const u32x2*)(bV + vrow * 128 +
                                           ((wk * 64 + j * 32 + 8 * g) ^ ((vrow & 7) << 4)));
                s16x4 vfj = __builtin_bit_cast(s16x4, vv);
                MFMA16(o[0][dj], pa[0][j], vfj);
                MFMA16(o[1][dj], pa[1][j], vfj);
            }
        }

        // ---- write next tile into the other buffer (read last in iter t-1)
        if (t < N_ / 64 - 1) {
            unsigned char* nK = smem + ((t + 1) & 1) * 8192;
            unsigned char* nV = smem + 16384 + ((t + 1) & 1) * 8192;
            *(u32x4*)(nK + srow * 128 + ssw) = kreg;
            *(u32x4*)(nV + srow * 128 + ssw) = vreg;
        }
        __syncthreads();
    }

    // ---- combine kv-halves: wk=1 dumps partials to LDS, wk=0 adds + writes AO.
    // (loop's final __syncthreads() already fenced the staging buffers)
    unsigned char* cb = smem + ((size_t)(wq * 64 + lane)) * 160;
    if (wk == 1) {
#pragma unroll
        for (int u = 0; u < 2; u++)
#pragma unroll
            for (int dj = 0; dj < 4; dj++)
                *(f32x4*)(cb + (u * 4 + dj) * 16) = o[u][dj];
        *(f32x4*)(cb + 128) = osum[0];
        *(f32x4*)(cb + 144) = osum[1];
    }
    __syncthreads();
    if (wk == 0) {
#pragma unroll
        for (int u = 0; u < 2; u++)
#pragma unroll
            for (int dj = 0; dj < 4; dj++)
                o[u][dj] += *(const f32x4*)(cb + (u * 4 + dj) * 16);
        osum[0] += *(const f32x4*)(cb + 128);
        osum[1] += *(const f32x4*)(cb + 144);

        const int b = bh >> 3, h = bh & 7;
#pragma unroll
        for (int u = 0; u < 2; u++)
#pragma unroll
            for (int r = 0; r < 4; r++) {
                float inv = 1.0f / osum[u][r];
                int n = q0 + u * 16 + (g << 2) + r;
#pragma unroll
                for (int dj = 0; dj < 4; dj++) {
                    int col = h * HD_ + dj * 16 + c;
                    AO[((size_t)(b * N_ + n)) * C_ + col] = f2bf(o[u][dj][r] * inv);
                }
            }
    }
}

// ---------------------------------------------------------------- launch
extern "C" void kernel_launch(void* const* d_in, const int* in_sizes, int n_in,
                              void* d_out, int out_size, void* d_ws, size_t ws_size,
                              hipStream_t stream) {
    const float* x = (const float*)d_in[0];
    const float* w_qkv = (const float*)d_in[1];
    const float* b_qkv = (const float*)d_in[2];
    const float* w_proj = (const float*)d_in[3];
    const float* b_proj = (const float*)d_in[4];
    float* out = (float*)d_out;

    // workspace layout (18.9 MB): xb (reused as AO) | wqb | wpb | Vt
    unsigned char* ws = (unsigned char*)d_ws;
    unsigned short* xb = (unsigned short*)ws;                       // 8192*512 bf16 (8.39MB)
    unsigned short* AO = xb;                                        // reuse after GEMM1
    unsigned short* wqb = (unsigned short*)(ws + 8388608);          // 1536*512 bf16
    unsigned short* wpb = (unsigned short*)(ws + 8388608 + 1572864);// 512*512 bf16
    unsigned short* Vt = (unsigned short*)(ws + 8388608 + 1572864 + 524288); // (B,H,64,N) bf16

    // d_out (16.78MB f32) doubles as scratch for Q,K bf16 (8.39MB each); proj GEMM
    // fully overwrites it at the end.
    unsigned short* Qb = (unsigned short*)d_out;
    unsigned short* Kb = Qb + (size_t)B_ * H_ * N_ * HD_;

    const int NALL = (B_ * N_ * C_ + 3 * C_ * C_ + C_ * C_) / 4;
    cvt_all<<<(NALL + 255) / 256, 256, 0, stream>>>(x, w_qkv, w_proj, xb, wqb, wpb);

    gemm_bt<0><<<dim3(12, 64), 256, 0, stream>>>(xb, wqb, b_qkv, nullptr, Qb, Kb, Vt);
    attn_fwd<<<dim3(16, 32), 512, 0, stream>>>(Qb, Kb, Vt, AO);
    gemm_bt<1><<<dim3(4, 64), 256, 0, stream>>>(AO, wpb, b_proj, out, nullptr, nullptr, nullptr);
}